// Round 15
// baseline (220.755 us; speedup 1.0000x reference)
//
#include <hip/hip_runtime.h>

#define TTHR 0.001f
#define QSC2 0.25503486f              // (1/sqrt(32)) * log2(e)  -> scores in log2 domain
#define CAP 16
#define YSCALE 8388608.0f             // 2^23
#define YINV   1.1920928955078125e-07f // 2^-23

#if __has_builtin(__builtin_amdgcn_exp2f)
#define EXP2(x) __builtin_amdgcn_exp2f(x)
#else
#define EXP2(x) __expf((x) * 0.6931471805599453f)
#endif

typedef _Float16 half4v __attribute__((ext_vector_type(4)));
typedef _Float16 half8v __attribute__((ext_vector_type(8)));
typedef float f32x4 __attribute__((ext_vector_type(4)));

// XCD-aware block swizzle: contiguous logical range per XCD (grid % 8 == 0).
__device__ __forceinline__ int xcd_bid() {
  return (blockIdx.x & 7) * ((int)gridDim.x >> 3) + ((int)blockIdx.x >> 3);
}

// ---- stage a 128x64-half tile into LDS, XOR-swizzled (256 threads) ----
// LDS granule (row, x) holds source granule (row, x ^ (row&7)); 16B granules.
// global_load_lds writes linearly (wave base + lane*16) -> inverse perm on source.
__device__ __forceinline__ void stage_tile_s(const _Float16* __restrict__ gsrc,
                                             int rowstride, _Float16* lds, int tid)
{
  const int lane = tid & 63;
  const int w4 = (tid >> 6) << 2;
#pragma unroll
  for (int r = 0; r < 4; ++r) {
    const int p = (w4 + r) * 64 + lane;
    const int row = p >> 3, xg = p & 7;
    __builtin_amdgcn_global_load_lds(
        (const __attribute__((address_space(1))) void*)(gsrc + row * rowstride + ((xg ^ (row & 7)) << 3)),
        (__attribute__((address_space(3))) void*)(lds + (w4 + r) * 512),
        16, 0, 0);
  }
}

// ---- stage a 64x64-half tile (256 threads) ----
__device__ __forceinline__ void stage_tile64(const _Float16* __restrict__ gsrc,
                                             int rowstride, _Float16* lds, int tid)
{
  const int lane = tid & 63;
  const int w2 = (tid >> 6) << 1;
#pragma unroll
  for (int r = 0; r < 2; ++r) {
    const int p = (w2 + r) * 64 + lane;
    const int row = p >> 3, xg = p & 7;
    __builtin_amdgcn_global_load_lds(
        (const __attribute__((address_space(1))) void*)(gsrc + row * rowstride + ((xg ^ (row & 7)) << 3)),
        (__attribute__((address_space(3))) void*)(lds + (w2 + r) * 512),
        16, 0, 0);
  }
}

// ---- 512-thread: 128x64 tile (2 granules/thread) ----
__device__ __forceinline__ void stage_k128_512(const _Float16* __restrict__ gsrc,
                                               _Float16* lds, int tid)
{
  const int lane = tid & 63, w = tid >> 6;
#pragma unroll
  for (int r = 0; r < 2; ++r) {
    const int p = ((w << 1) + r) * 64 + lane;
    const int row = p >> 3, xg = p & 7;
    __builtin_amdgcn_global_load_lds(
        (const __attribute__((address_space(1))) void*)(gsrc + row * 64 + ((xg ^ (row & 7)) << 3)),
        (__attribute__((address_space(3))) void*)(lds + ((w << 1) + r) * 512),
        16, 0, 0);
  }
}

// ---------------- conversion kernels ----------------
// hi-only split: the lo half is no longer consumed anywhere for x.
__global__ __launch_bounds__(256) void k_split_rm(
    const float* __restrict__ in, _Float16* __restrict__ oh, int n4)
{
  const int i = blockIdx.x * 256 + threadIdx.x;
  if (i >= n4) return;
  float4 v = ((const float4*)in)[i];
  half4v h = {(_Float16)v.x, (_Float16)v.y, (_Float16)v.z, (_Float16)v.w};
  ((half4v*)oh)[i] = h;
}

__global__ __launch_bounds__(256) void k_split_tr(
    const float* __restrict__ in, _Float16* __restrict__ oh,
    _Float16* __restrict__ ol, int K, int N)
{
  __shared__ float t[32][33];
  const int nb = N >> 5;
  const int n0 = (blockIdx.x % nb) << 5, k0 = (blockIdx.x / nb) << 5;
  const int r = threadIdx.x >> 3, c4 = (threadIdx.x & 7) << 2;
  float4 v = *(const float4*)&in[(k0 + r) * N + n0 + c4];
  t[r][c4] = v.x; t[r][c4 + 1] = v.y; t[r][c4 + 2] = v.z; t[r][c4 + 3] = v.w;
  __syncthreads();
  float a0 = t[c4][r], a1 = t[c4 + 1][r], a2 = t[c4 + 2][r], a3 = t[c4 + 3][r];
  half4v h = {(_Float16)a0, (_Float16)a1, (_Float16)a2, (_Float16)a3};
  *(half4v*)&oh[(n0 + r) * K + k0 + c4] = h;
  if (ol != nullptr) {
    half4v l = {(_Float16)(a0 - (float)h[0]), (_Float16)(a1 - (float)h[1]),
                (_Float16)(a2 - (float)h[2]), (_Float16)(a3 - (float)h[3])};
    *(half4v*)&ol[(n0 + r) * K + k0 + c4] = l;
  }
}

// ------- split-fp16 MFMA GEMM, 128x64 tile, 3-buf counted-vmcnt pipeline ----
// NPASS=1: Ah*Bh.  NPASS=2: Ah*Bh + Ah*Bl.  NPASS=3: + Al*Bh.
template<int EPI, int NPASS>
__global__ __launch_bounds__(256) void k_gemm_split(
    const _Float16* __restrict__ Ah, const _Float16* __restrict__ Al,
    const _Float16* __restrict__ Bh, const _Float16* __restrict__ Bl,
    const float* __restrict__ bias, int K, int kclog, int nbn,
    float* __restrict__ out, _Float16* __restrict__ Qs,
    _Float16* __restrict__ Ks, float* __restrict__ Vp)
{
  __shared__ __align__(16) _Float16 Asm[3][8192];
  __shared__ __align__(16) _Float16 Bsm[3][4096];
  const int tid = threadIdx.x, lane = tid & 63, w = tid >> 6;
  const int wr = w >> 1, wc = w & 1;
  const int lrow = lane & 15, lk = lane >> 4;
  const int bid = xcd_bid();
  const int mt = bid / nbn, ct = bid % nbn;
  const int m0 = mt << 7, c0 = ct << 6;

  const int nch = NPASS << kclog;
  const int kcm = (1 << kclog) - 1;

  auto abase = [&](int c2) -> const _Float16* {
    const int phase = c2 >> kclog, kc = c2 & kcm;
    const _Float16* A = (phase == 2) ? Al : Ah;
    return A + (size_t)m0 * K + (kc << 6);
  };
  auto bbase = [&](int c2) -> const _Float16* {
    const int phase = c2 >> kclog, kc = c2 & kcm;
    const _Float16* B = (phase == 1) ? Bl : Bh;
    return B + (size_t)c0 * K + (kc << 6);
  };

  // prologue: 2 tiles in flight
  stage_tile_s(abase(0), K, Asm[0], tid);
  stage_tile64(bbase(0), K, Bsm[0], tid);
  stage_tile_s(abase(1), K, Asm[1], tid);
  stage_tile64(bbase(1), K, Bsm[1], tid);

  f32x4 acc[4][2] = {};
  int cur = 0;
#pragma unroll 1
  for (int ch = 0; ch < nch; ++ch) {
    if (ch + 1 < nch) { asm volatile("s_waitcnt vmcnt(6)" ::: "memory"); }
    else              { asm volatile("s_waitcnt vmcnt(0)" ::: "memory"); }
    __builtin_amdgcn_s_barrier();
    __builtin_amdgcn_sched_barrier(0);
#pragma unroll
    for (int ks = 0; ks < 2; ++ks) {
      half8v af[4], bf[2];
#pragma unroll
      for (int mi = 0; mi < 4; ++mi) {
        const int row = (wr << 6) + (mi << 4) + lrow;
        const int xg = ((ks << 2) + lk) ^ (row & 7);
        af[mi] = *(const half8v*)&Asm[cur][((row << 3) + xg) << 3];
      }
#pragma unroll
      for (int ni = 0; ni < 2; ++ni) {
        const int col = (wc << 5) + (ni << 4) + lrow;
        const int xg = ((ks << 2) + lk) ^ (col & 7);
        bf[ni] = *(const half8v*)&Bsm[cur][((col << 3) + xg) << 3];
      }
#pragma unroll
      for (int mi = 0; mi < 4; ++mi)
#pragma unroll
        for (int ni = 0; ni < 2; ++ni)
          acc[mi][ni] = __builtin_amdgcn_mfma_f32_16x16x32_f16(af[mi], bf[ni], acc[mi][ni], 0, 0, 0);
    }
    if (ch + 2 < nch) {
      int nb = cur + 2; if (nb >= 3) nb -= 3;
      stage_tile_s(abase(ch + 2), K, Asm[nb], tid);
      stage_tile64(bbase(ch + 2), K, Bsm[nb], tid);
    }
    ++cur; if (cur == 3) cur = 0;
  }

#pragma unroll
  for (int ni = 0; ni < 2; ++ni) {
    const int c = c0 + (wc << 5) + (ni << 4) + lrow;
    const float bv = bias[c];
    if (EPI == 0) {
#pragma unroll
      for (int mi = 0; mi < 4; ++mi)
#pragma unroll
        for (int reg = 0; reg < 4; ++reg) {
          const int m = m0 + (wr << 6) + (mi << 4) + (lk << 2) + reg;
          out[m * 1024 + c] = acc[mi][ni][reg] * YINV + bv;
        }
    } else {
      const int part = c >> 8, cc = c & 255;
      const int h = cc >> 5, d = cc & 31;
#pragma unroll
      for (int mi = 0; mi < 4; ++mi)
#pragma unroll
        for (int reg = 0; reg < 4; ++reg) {
          const int m = m0 + (wr << 6) + (mi << 4) + (lk << 2) + reg;
          const int b = m >> 12, n = (m >> 2) & 1023, l = m & 3;
          const int panel = b * 32 + l * 8 + h;
          float v = acc[mi][ni][reg] + bv;
          if (part == 2) {
            Vp[(panel << 15) + n * 32 + d] = v;
          } else {
            _Float16* dst = part ? Ks : Qs;
            if (!part) v *= QSC2;   // fold 1/sqrt(D) * log2(e) into Q
            _Float16 hv = (_Float16)v;
            _Float16 lv = (_Float16)(v - (float)hv);
            dst[(panel << 16) + n * 64 + d] = hv;
            dst[(panel << 16) + n * 64 + 32 + d] = lv;
          }
        }
    }
  }
}

// -------- fused attention: 32-row blocks, hi-packed Q, r9-proven loop ------
// grid 1024 (bh x 32 rowtiles of 32 rows), 512 thr = 8 col-waves; wave tile
// 32 rows x 16 cols (mi=2, ni=1). Q hi halves packed 2-rows-per-LDS-row
// (8 KB, conflict-free: xu=((row&1)<<2)|lk spans 0..7 per 8-lane group);
// K 2-buf 32 KB. LDS ~41.5 KB -> 3 blocks/CU = 24 waves/CU (vs r9's 16).
// 2-split score both passes: s ~= qh*kh + qh*kl (validated, absmax 1.5e-11).
// pass1: it in [0,32): l = it>>3, ct = it&7  -> Z row sums (LDS atomics)
// pass2: it in [32,64): ct = (it-32)>>2, l = (it-32)&3 -> product, emit
// prod_l relu(2^s/Z - T) == (prod_l max(2^s - T*Z_l, 0)) / prod_l Z_l
__global__ __launch_bounds__(512) void k_att(
    const _Float16* __restrict__ Qs, const _Float16* __restrict__ Ks,
    int* __restrict__ ccnt, unsigned short* __restrict__ cidx,
    float* __restrict__ cval)
{
  __shared__ __align__(16) _Float16 Qres[4][1024];  // 8 KB (hi, 2-row-packed)
  __shared__ __align__(16) _Float16 Kb[2][8192];    // 32 KB
  __shared__ float Zsh[4][32];
  __shared__ float tzs[4][32];
  __shared__ float rz[32];
  __shared__ int lcnt[32];
  const int tid = threadIdx.x, lane = tid & 63, wc = tid >> 6;  // 8 col-waves
  const int lrow = lane & 15, lk = lane >> 4;
  const int s = (blockIdx.x & 7) * 128 + ((int)blockIdx.x >> 3);
  const int bh = s >> 5, rt = s & 31;
  const int b = bh >> 3, h = bh & 7;
  const int pbase = b * 32 + h;                     // level stride = 8 panels

  auto kaddr = [&](int t) -> const _Float16* {
    const int l  = (t < 32) ? (t >> 3) : ((t - 32) & 3);
    const int ct = (t < 32) ? (t & 7) : ((t - 32) >> 2);
    return Ks + ((size_t)(pbase + l * 8) << 16) + (ct << 13);
  };

  // Q hi-packed staging: 512 granules total (4 lv x 16 LDS-rows x 8 granules),
  // 1/thread. LDS (lv, r', x) holds source (row = 2r' + (xu>>2), granule xu&3)
  // with xu = x ^ (r'&7).
  {
    const int lv = tid >> 7, p = tid & 127;
    const int rp = p >> 3, x = p & 7;
    const int xu = x ^ (rp & 7);
    const int row = (rp << 1) + (xu >> 2), sg = xu & 3;
    __builtin_amdgcn_global_load_lds(
        (const __attribute__((address_space(1))) void*)(
            Qs + ((size_t)(pbase + lv * 8) << 16) + (rt << 11) + row * 64 + (sg << 3)),
        (__attribute__((address_space(3))) void*)((_Float16*)Qres + ((tid >> 6) << 9)),
        16, 0, 0);
  }
  stage_k128_512(kaddr(0), Kb[0], tid);
  if (tid < 128) Zsh[tid >> 5][tid & 31] = 0.0f;
  __syncthreads();

  // 2-split: A reads packed qh; B reads kh then kl.
  const int kstB[2] = {0, 4};
  float rsum[2][4] = {};
  float prod[2][4];

#pragma unroll 1
  for (int it = 0; it < 64; ++it) {
    const int cur = it & 1;
    const int pass = it >> 5;
    const int l  = pass ? ((it - 32) & 3) : (it >> 3);
    const int ct = pass ? ((it - 32) >> 2) : (it & 7);
    if (it < 63) stage_k128_512(kaddr(it + 1), Kb[cur ^ 1], tid);
    if (pass && l == 0 && tid < 32) lcnt[tid] = 0;

    // A fragments from packed Q: row in [0,32), r' = row>>1,
    // x = (((row&1)<<2)|lk) ^ (r'&7)
    half8v af[2];
#pragma unroll
    for (int mi = 0; mi < 2; ++mi) {
      const int row = (mi << 4) + lrow;
      const int rp = row >> 1;
      const int x = (((row & 1) << 2) | lk) ^ (rp & 7);
      af[mi] = *(const half8v*)&Qres[l][(rp << 6) + (x << 3)];
    }
    f32x4 acc[2] = {};
#pragma unroll
    for (int ks = 0; ks < 2; ++ks) {
      const int col = (wc << 4) + lrow;
      const int xg = (kstB[ks] + lk) ^ (col & 7);
      half8v bf = *(const half8v*)&Kb[cur][((col << 3) + xg) << 3];
#pragma unroll
      for (int mi = 0; mi < 2; ++mi)
        acc[mi] = __builtin_amdgcn_mfma_f32_16x16x32_f16(af[mi], bf, acc[mi], 0, 0, 0);
    }

    if (!pass) {
#pragma unroll
      for (int mi = 0; mi < 2; ++mi)
#pragma unroll
        for (int reg = 0; reg < 4; ++reg)
          rsum[mi][reg] += EXP2(acc[mi][reg]);
      if ((it & 7) == 7) {                    // end of level-l sweep
#pragma unroll
        for (int mi = 0; mi < 2; ++mi)
#pragma unroll
          for (int reg = 0; reg < 4; ++reg) {
            float v = rsum[mi][reg];
            v += __shfl_xor(v, 1, 64);
            v += __shfl_xor(v, 2, 64);
            v += __shfl_xor(v, 4, 64);
            v += __shfl_xor(v, 8, 64);
            if (lrow == 0)
              atomicAdd(&Zsh[l][(mi << 4) + (lk << 2) + reg], v);
            rsum[mi][reg] = 0.0f;
          }
      }
    } else {
#pragma unroll
      for (int mi = 0; mi < 2; ++mi)
#pragma unroll
        for (int reg = 0; reg < 4; ++reg) {
          const float tzv = tzs[l][(mi << 4) + (lk << 2) + reg];
          const float e = fmaxf(EXP2(acc[mi][reg]) - tzv, 0.0f);
          prod[mi][reg] = (l == 0) ? e : prod[mi][reg] * e;
        }
      if (l == 3) {
#pragma unroll
        for (int mi = 0; mi < 2; ++mi)
#pragma unroll
          for (int reg = 0; reg < 4; ++reg) {
            const int rloc = (mi << 4) + (lk << 2) + reg;
            const float v = prod[mi][reg] * rz[rloc];
            if (v > 0.0f) {
              const int slot = atomicAdd(&lcnt[rloc], 1);
              if (slot < CAP) {
                const int rowc = (bh << 10) + (rt << 5) + rloc;
                const int mglob = (ct << 7) + (wc << 4) + lrow;
                cidx[(rowc * 8 + ct) * CAP + slot] = (unsigned short)mglob;
                cval[(rowc * 8 + ct) * CAP + slot] = v * YSCALE;
              }
            }
          }
        __syncthreads();
        if (tid < 32)
          ccnt[((bh << 10) + (rt << 5) + tid) * 8 + ct] = min(lcnt[tid], CAP);
      }
    }
    __syncthreads();
    if (it == 31) {                          // pass boundary: build tz, rz
      if (tid < 128) tzs[tid >> 5][tid & 31] = TTHR * Zsh[tid >> 5][tid & 31];
      if (tid < 32)
        rz[tid] = 1.0f / ((Zsh[0][tid] * Zsh[1][tid]) * (Zsh[2][tid] * Zsh[3][tid]));
      __syncthreads();
    }
  }
}

// ---------------- K4: sparse PV gather -> fp16 ys (hi only) ----------------
__global__ __launch_bounds__(512) void k_pv(
    const float* __restrict__ Vp, const int* __restrict__ ccnt,
    const unsigned short* __restrict__ cidx, const float* __restrict__ cval,
    _Float16* __restrict__ ysh)
{
  const int rowc = blockIdx.x * 8 + (threadIdx.x >> 6);
  const int lane = threadIdx.x & 63;
  const int bh = rowc >> 10, n = rowc & 1023;
  const int b = bh >> 3, h = bh & 7;
  const int l0 = lane >> 5, d = lane & 31;
  const float* vA = Vp + ((b * 32 + l0 * 8 + h) << 15) + d;
  const float* vB = vA + (16 << 15);
  float y0 = 0.f, y1 = 0.f;
  for (int mcj = 0; mcj < 8; ++mcj) {
    const int cnt = min(ccnt[rowc * 8 + mcj], CAP);
    const int off = (rowc * 8 + mcj) * CAP;
    for (int i = 0; i < cnt; ++i) {
      const int m = cidx[off + i];
      const float wv = cval[off + i];
      y0 = fmaf(wv, vA[m * 32], y0);
      y1 = fmaf(wv, vB[m * 32], y1);
    }
  }
  const int idx = ((b << 10) + n) * 1024 + l0 * 256 + h * 32 + d;
  ysh[idx] = (_Float16)y0;
  ysh[idx + 512] = (_Float16)y1;
}

extern "C" void kernel_launch(void* const* d_in, const int* in_sizes, int n_in,
                              void* d_out, int out_size, void* d_ws, size_t ws_size,
                              hipStream_t stream)
{
  const float* x  = (const float*)d_in[0];
  const float* Wc = (const float*)d_in[1];
  const float* bc = (const float*)d_in[2];
  const float* Wp = (const float*)d_in[3];
  const float* bp = (const float*)d_in[4];
  float* out = (float*)d_out;
  (void)in_sizes; (void)n_in; (void)out_size;

  if (ws_size < 98828288ull) return;
  char* wsb = (char*)d_ws;
  float*          Vp   = (float*)wsb;
  _Float16*       Qs   = (_Float16*)(wsb + 16777216);
  _Float16*       Ks   = (_Float16*)(wsb + 33554432);
  _Float16*       xh   = (_Float16*)(wsb + 50855936);  // also ysh (disjoint lifetimes)
  int*            ccnt = (int*)(wsb + 67633152);
  unsigned short* cidx = (unsigned short*)(wsb + 68681728);
  float*          cval = (float*)(wsb + 77070336);
  _Float16*       Wch  = (_Float16*)(wsb + 93847552);
  _Float16*       Wcl  = (_Float16*)(wsb + 94240768);
  _Float16*       Wph  = (_Float16*)(wsb + 94633984);

  k_split_rm<<<dim3(4096), dim3(256), 0, stream>>>(x, xh, 1048576);
  k_split_tr<<<dim3(192), dim3(256), 0, stream>>>(Wc, Wch, Wcl, 256, 768);
  k_split_tr<<<dim3(1024), dim3(256), 0, stream>>>(Wp, Wph, nullptr, 1024, 1024);
  // qkv: M=16384 K=256 N=768; BN=64 -> nbn=12, grid 128*12=1536; 2-pass
  k_gemm_split<1, 2><<<dim3(1536), dim3(256), 0, stream>>>(
      xh, nullptr, Wch, Wcl, bc, 256, 2, 12, nullptr, Qs, Ks, Vp);
  // fused Z + threshold/product/emit (32-row blocks, hi-packed Q, 3 blk/CU)
  k_att<<<dim3(1024), dim3(512), 0, stream>>>(Qs, Ks, ccnt, cidx, cval);
  k_pv<<<dim3(4096), dim3(512), 0, stream>>>(Vp, ccnt, cidx, cval, xh);
  // proj: M=4096 K=1024 N=1024; BN=64 -> nbn=16, grid 32*16=512; 1-pass fp16
  k_gemm_split<0, 1><<<dim3(512), dim3(256), 0, stream>>>(
      xh, nullptr, Wph, nullptr, bp, 1024, 4, 16, out, nullptr, nullptr, nullptr);
}

// Round 16
// 190.697 us; speedup vs baseline: 1.1576x; 1.1576x over previous
//
#include <hip/hip_runtime.h>

#define TTHR 0.001f
#define QSC2 0.25503486f              // (1/sqrt(32)) * log2(e)  -> scores in log2 domain
#define CAP 16
#define YSCALE 8388608.0f             // 2^23
#define YINV   1.1920928955078125e-07f // 2^-23

#if __has_builtin(__builtin_amdgcn_exp2f)
#define EXP2(x) __builtin_amdgcn_exp2f(x)
#else
#define EXP2(x) __expf((x) * 0.6931471805599453f)
#endif

typedef _Float16 half4v __attribute__((ext_vector_type(4)));
typedef _Float16 half8v __attribute__((ext_vector_type(8)));
typedef float f32x4 __attribute__((ext_vector_type(4)));

// XCD-aware block swizzle: contiguous logical range per XCD (grid % 8 == 0).
__device__ __forceinline__ int xcd_bid() {
  return (blockIdx.x & 7) * ((int)gridDim.x >> 3) + ((int)blockIdx.x >> 3);
}

// ---- stage a 128x64-half tile into LDS, XOR-swizzled (256 threads) ----
// LDS granule (row, x) holds source granule (row, x ^ (row&7)); 16B granules.
// global_load_lds writes linearly (wave base + lane*16) -> inverse perm on source.
__device__ __forceinline__ void stage_tile_s(const _Float16* __restrict__ gsrc,
                                             int rowstride, _Float16* lds, int tid)
{
  const int lane = tid & 63;
  const int w4 = (tid >> 6) << 2;
#pragma unroll
  for (int r = 0; r < 4; ++r) {
    const int p = (w4 + r) * 64 + lane;
    const int row = p >> 3, xg = p & 7;
    __builtin_amdgcn_global_load_lds(
        (const __attribute__((address_space(1))) void*)(gsrc + row * rowstride + ((xg ^ (row & 7)) << 3)),
        (__attribute__((address_space(3))) void*)(lds + (w4 + r) * 512),
        16, 0, 0);
  }
}

// ---- stage a 64x64-half tile (256 threads) ----
__device__ __forceinline__ void stage_tile64(const _Float16* __restrict__ gsrc,
                                             int rowstride, _Float16* lds, int tid)
{
  const int lane = tid & 63;
  const int w2 = (tid >> 6) << 1;
#pragma unroll
  for (int r = 0; r < 2; ++r) {
    const int p = (w2 + r) * 64 + lane;
    const int row = p >> 3, xg = p & 7;
    __builtin_amdgcn_global_load_lds(
        (const __attribute__((address_space(1))) void*)(gsrc + row * rowstride + ((xg ^ (row & 7)) << 3)),
        (__attribute__((address_space(3))) void*)(lds + (w2 + r) * 512),
        16, 0, 0);
  }
}

// ---- 512-thread variants (8 waves): 64x64 tile (1 granule/thread) ----
__device__ __forceinline__ void stage_q64_512(const _Float16* __restrict__ gsrc,
                                              _Float16* lds, int tid)
{
  const int lane = tid & 63, w = tid >> 6;
  const int p = (w << 6) + lane;
  const int row = p >> 3, xg = p & 7;
  __builtin_amdgcn_global_load_lds(
      (const __attribute__((address_space(1))) void*)(gsrc + row * 64 + ((xg ^ (row & 7)) << 3)),
      (__attribute__((address_space(3))) void*)(lds + (w << 9)),
      16, 0, 0);
}

// ---- 512-thread: 128x64 tile (2 granules/thread) ----
__device__ __forceinline__ void stage_k128_512(const _Float16* __restrict__ gsrc,
                                               _Float16* lds, int tid)
{
  const int lane = tid & 63, w = tid >> 6;
#pragma unroll
  for (int r = 0; r < 2; ++r) {
    const int p = ((w << 1) + r) * 64 + lane;
    const int row = p >> 3, xg = p & 7;
    __builtin_amdgcn_global_load_lds(
        (const __attribute__((address_space(1))) void*)(gsrc + row * 64 + ((xg ^ (row & 7)) << 3)),
        (__attribute__((address_space(3))) void*)(lds + ((w << 1) + r) * 512),
        16, 0, 0);
  }
}

// ---------------- conversion kernels ----------------
// hi-only split: the lo half is no longer consumed anywhere for x.
__global__ __launch_bounds__(256) void k_split_rm(
    const float* __restrict__ in, _Float16* __restrict__ oh, int n4)
{
  const int i = blockIdx.x * 256 + threadIdx.x;
  if (i >= n4) return;
  float4 v = ((const float4*)in)[i];
  half4v h = {(_Float16)v.x, (_Float16)v.y, (_Float16)v.z, (_Float16)v.w};
  ((half4v*)oh)[i] = h;
}

__global__ __launch_bounds__(256) void k_split_tr(
    const float* __restrict__ in, _Float16* __restrict__ oh,
    _Float16* __restrict__ ol, int K, int N)
{
  __shared__ float t[32][33];
  const int nb = N >> 5;
  const int n0 = (blockIdx.x % nb) << 5, k0 = (blockIdx.x / nb) << 5;
  const int r = threadIdx.x >> 3, c4 = (threadIdx.x & 7) << 2;
  float4 v = *(const float4*)&in[(k0 + r) * N + n0 + c4];
  t[r][c4] = v.x; t[r][c4 + 1] = v.y; t[r][c4 + 2] = v.z; t[r][c4 + 3] = v.w;
  __syncthreads();
  float a0 = t[c4][r], a1 = t[c4 + 1][r], a2 = t[c4 + 2][r], a3 = t[c4 + 3][r];
  half4v h = {(_Float16)a0, (_Float16)a1, (_Float16)a2, (_Float16)a3};
  *(half4v*)&oh[(n0 + r) * K + k0 + c4] = h;
  if (ol != nullptr) {
    half4v l = {(_Float16)(a0 - (float)h[0]), (_Float16)(a1 - (float)h[1]),
                (_Float16)(a2 - (float)h[2]), (_Float16)(a3 - (float)h[3])};
    *(half4v*)&ol[(n0 + r) * K + k0 + c4] = l;
  }
}

// ------- split-fp16 MFMA GEMM, 128x64 tile, 3-buf counted-vmcnt pipeline ----
// NPASS=1: Ah*Bh.  NPASS=2: Ah*Bh + Ah*Bl.  NPASS=3: + Al*Bh.
template<int EPI, int NPASS>
__global__ __launch_bounds__(256) void k_gemm_split(
    const _Float16* __restrict__ Ah, const _Float16* __restrict__ Al,
    const _Float16* __restrict__ Bh, const _Float16* __restrict__ Bl,
    const float* __restrict__ bias, int K, int kclog, int nbn,
    float* __restrict__ out, _Float16* __restrict__ Qs,
    _Float16* __restrict__ Ks, float* __restrict__ Vp)
{
  __shared__ __align__(16) _Float16 Asm[3][8192];
  __shared__ __align__(16) _Float16 Bsm[3][4096];
  const int tid = threadIdx.x, lane = tid & 63, w = tid >> 6;
  const int wr = w >> 1, wc = w & 1;
  const int lrow = lane & 15, lk = lane >> 4;
  const int bid = xcd_bid();
  const int mt = bid / nbn, ct = bid % nbn;
  const int m0 = mt << 7, c0 = ct << 6;

  const int nch = NPASS << kclog;
  const int kcm = (1 << kclog) - 1;

  auto abase = [&](int c2) -> const _Float16* {
    const int phase = c2 >> kclog, kc = c2 & kcm;
    const _Float16* A = (phase == 2) ? Al : Ah;
    return A + (size_t)m0 * K + (kc << 6);
  };
  auto bbase = [&](int c2) -> const _Float16* {
    const int phase = c2 >> kclog, kc = c2 & kcm;
    const _Float16* B = (phase == 1) ? Bl : Bh;
    return B + (size_t)c0 * K + (kc << 6);
  };

  // prologue: 2 tiles in flight
  stage_tile_s(abase(0), K, Asm[0], tid);
  stage_tile64(bbase(0), K, Bsm[0], tid);
  stage_tile_s(abase(1), K, Asm[1], tid);
  stage_tile64(bbase(1), K, Bsm[1], tid);

  f32x4 acc[4][2] = {};
  int cur = 0;
#pragma unroll 1
  for (int ch = 0; ch < nch; ++ch) {
    if (ch + 1 < nch) { asm volatile("s_waitcnt vmcnt(6)" ::: "memory"); }
    else              { asm volatile("s_waitcnt vmcnt(0)" ::: "memory"); }
    __builtin_amdgcn_s_barrier();
    __builtin_amdgcn_sched_barrier(0);
#pragma unroll
    for (int ks = 0; ks < 2; ++ks) {
      half8v af[4], bf[2];
#pragma unroll
      for (int mi = 0; mi < 4; ++mi) {
        const int row = (wr << 6) + (mi << 4) + lrow;
        const int xg = ((ks << 2) + lk) ^ (row & 7);
        af[mi] = *(const half8v*)&Asm[cur][((row << 3) + xg) << 3];
      }
#pragma unroll
      for (int ni = 0; ni < 2; ++ni) {
        const int col = (wc << 5) + (ni << 4) + lrow;
        const int xg = ((ks << 2) + lk) ^ (col & 7);
        bf[ni] = *(const half8v*)&Bsm[cur][((col << 3) + xg) << 3];
      }
#pragma unroll
      for (int mi = 0; mi < 4; ++mi)
#pragma unroll
        for (int ni = 0; ni < 2; ++ni)
          acc[mi][ni] = __builtin_amdgcn_mfma_f32_16x16x32_f16(af[mi], bf[ni], acc[mi][ni], 0, 0, 0);
    }
    if (ch + 2 < nch) {
      int nb = cur + 2; if (nb >= 3) nb -= 3;
      stage_tile_s(abase(ch + 2), K, Asm[nb], tid);
      stage_tile64(bbase(ch + 2), K, Bsm[nb], tid);
    }
    ++cur; if (cur == 3) cur = 0;
  }

#pragma unroll
  for (int ni = 0; ni < 2; ++ni) {
    const int c = c0 + (wc << 5) + (ni << 4) + lrow;
    const float bv = bias[c];
    if (EPI == 0) {
#pragma unroll
      for (int mi = 0; mi < 4; ++mi)
#pragma unroll
        for (int reg = 0; reg < 4; ++reg) {
          const int m = m0 + (wr << 6) + (mi << 4) + (lk << 2) + reg;
          out[m * 1024 + c] = acc[mi][ni][reg] * YINV + bv;
        }
    } else {
      const int part = c >> 8, cc = c & 255;
      const int h = cc >> 5, d = cc & 31;
#pragma unroll
      for (int mi = 0; mi < 4; ++mi)
#pragma unroll
        for (int reg = 0; reg < 4; ++reg) {
          const int m = m0 + (wr << 6) + (mi << 4) + (lk << 2) + reg;
          const int b = m >> 12, n = (m >> 2) & 1023, l = m & 3;
          const int panel = b * 32 + l * 8 + h;
          float v = acc[mi][ni][reg] + bv;
          if (part == 2) {
            Vp[(panel << 15) + n * 32 + d] = v;
          } else {
            _Float16* dst = part ? Ks : Qs;
            if (!part) v *= QSC2;   // fold 1/sqrt(D) * log2(e) into Q
            _Float16 hv = (_Float16)v;
            _Float16 lv = (_Float16)(v - (float)hv);
            dst[(panel << 16) + n * 64 + d] = hv;
            dst[(panel << 16) + n * 64 + 32 + d] = lv;
          }
        }
    }
  }
}

// -------- fused attention: pass1 Z row-sums, pass2 threshold/product/emit ----
// (r9 structure, best measured: 98 us) 512 thr = 8 waves (2 row x 4 col);
// block = 64 rows x 128 cols/tile. Q (4 levels) LDS-resident; K 2-buf.
// 2-split score both passes: s ~= qh*kh + qh*kl (validated, absmax 1.5e-11).
// pass1: it in [0,32): l = it>>3, ct = it&7  (level-major -> rsum is 8 regs)
// pass2: it in [32,64): ct = (it-32)>>2, l = (it-32)&3 (product across levels)
// prod_l relu(2^s/Z - T) == (prod_l max(2^s - T*Z_l, 0)) / prod_l Z_l
__global__ __launch_bounds__(512) void k_att(
    const _Float16* __restrict__ Qs, const _Float16* __restrict__ Ks,
    int* __restrict__ ccnt, unsigned short* __restrict__ cidx,
    float* __restrict__ cval)
{
  __shared__ __align__(16) _Float16 Qres[4][4096];
  __shared__ __align__(16) _Float16 Kb[2][8192];
  __shared__ float Zsh[4][64];
  __shared__ float tzs[4][64];
  __shared__ float rz[64];
  __shared__ int lcnt[64];
  const int tid = threadIdx.x, lane = tid & 63, w = tid >> 6;
  const int wr = w >> 2, wc = w & 3;
  const int lrow = lane & 15, lk = lane >> 4;
  const int s = (blockIdx.x & 7) * 64 + ((int)blockIdx.x >> 3);
  const int bh = s >> 4, rt = s & 15;
  const int b = bh >> 3, h = bh & 7;
  const int pbase = b * 32 + h;                     // level stride = 8 panels

#pragma unroll
  for (int l = 0; l < 4; ++l)
    stage_q64_512(Qs + ((pbase + l * 8) << 16) + (rt << 12), Qres[l], tid);
  stage_k128_512(Ks + (pbase << 16), Kb[0], tid);
  if (tid < 256) Zsh[tid >> 6][tid & 63] = 0.0f;
  __syncthreads();

  // 2-split: A always reads qh (granules 0-3); B reads kh then kl.
  const int kstB[2] = {0, 4};
  float rsum[2][4] = {};
  float prod[2][2][4];

#pragma unroll 1
  for (int it = 0; it < 64; ++it) {
    const int cur = it & 1;
    const int pass = it >> 5;
    const int l  = pass ? ((it - 32) & 3) : (it >> 3);
    const int ct = pass ? ((it - 32) >> 2) : (it & 7);
    if (it < 63) {
      const int t2 = it + 1;
      const int l2  = (t2 < 32) ? (t2 >> 3) : ((t2 - 32) & 3);
      const int ct2 = (t2 < 32) ? (t2 & 7) : ((t2 - 32) >> 2);
      stage_k128_512(Ks + ((pbase + l2 * 8) << 16) + (ct2 << 13), Kb[cur ^ 1], tid);
    }
    if (pass && l == 0 && tid < 64) lcnt[tid] = 0;

    f32x4 acc[2][2] = {};
#pragma unroll
    for (int ks = 0; ks < 2; ++ks) {
      half8v af[2], bf[2];
#pragma unroll
      for (int mi = 0; mi < 2; ++mi) {
        const int row = (wr << 5) + (mi << 4) + lrow;
        const int xg = lk ^ (row & 7);
        af[mi] = *(const half8v*)&Qres[l][((row << 3) + xg) << 3];
      }
#pragma unroll
      for (int ni = 0; ni < 2; ++ni) {
        const int col = (wc << 5) + (ni << 4) + lrow;
        const int xg = (kstB[ks] + lk) ^ (col & 7);
        bf[ni] = *(const half8v*)&Kb[cur][((col << 3) + xg) << 3];
      }
#pragma unroll
      for (int mi = 0; mi < 2; ++mi)
#pragma unroll
        for (int ni = 0; ni < 2; ++ni)
          acc[mi][ni] = __builtin_amdgcn_mfma_f32_16x16x32_f16(af[mi], bf[ni], acc[mi][ni], 0, 0, 0);
    }

    if (!pass) {
#pragma unroll
      for (int mi = 0; mi < 2; ++mi)
#pragma unroll
        for (int reg = 0; reg < 4; ++reg)
          rsum[mi][reg] += EXP2(acc[mi][0][reg]) + EXP2(acc[mi][1][reg]);
      if ((it & 7) == 7) {                    // end of level-l sweep
#pragma unroll
        for (int mi = 0; mi < 2; ++mi)
#pragma unroll
          for (int reg = 0; reg < 4; ++reg) {
            float v = rsum[mi][reg];
            v += __shfl_xor(v, 1, 64);
            v += __shfl_xor(v, 2, 64);
            v += __shfl_xor(v, 4, 64);
            v += __shfl_xor(v, 8, 64);
            if (lrow == 0)
              atomicAdd(&Zsh[l][(wr << 5) + (mi << 4) + (lk << 2) + reg], v);
            rsum[mi][reg] = 0.0f;
          }
      }
    } else {
#pragma unroll
      for (int mi = 0; mi < 2; ++mi)
#pragma unroll
        for (int reg = 0; reg < 4; ++reg) {
          const float tzv = tzs[l][(wr << 5) + (mi << 4) + (lk << 2) + reg];
#pragma unroll
          for (int ni = 0; ni < 2; ++ni) {
            const float e = fmaxf(EXP2(acc[mi][ni][reg]) - tzv, 0.0f);
            prod[mi][ni][reg] = (l == 0) ? e : prod[mi][ni][reg] * e;
          }
        }
      if (l == 3) {
#pragma unroll
        for (int mi = 0; mi < 2; ++mi)
#pragma unroll
          for (int ni = 0; ni < 2; ++ni)
#pragma unroll
            for (int reg = 0; reg < 4; ++reg) {
              const int rloc = (wr << 5) + (mi << 4) + (lk << 2) + reg;
              const float v = prod[mi][ni][reg] * rz[rloc];
              if (v > 0.0f) {
                const int slot = atomicAdd(&lcnt[rloc], 1);
                if (slot < CAP) {
                  const int rowc = (bh << 10) + (rt << 6) + rloc;
                  const int mglob = (ct << 7) + (wc << 5) + (ni << 4) + lrow;
                  cidx[(rowc * 8 + ct) * CAP + slot] = (unsigned short)mglob;
                  cval[(rowc * 8 + ct) * CAP + slot] = v * YSCALE;
                }
              }
            }
        __syncthreads();
        if (tid < 64)
          ccnt[((bh << 10) + (rt << 6) + tid) * 8 + ct] = min(lcnt[tid], CAP);
      }
    }
    __syncthreads();
    if (it == 31) {                          // pass boundary: build tz, rz
      if (tid < 256) tzs[tid >> 6][tid & 63] = TTHR * Zsh[tid >> 6][tid & 63];
      if (tid < 64)
        rz[tid] = 1.0f / ((Zsh[0][tid] * Zsh[1][tid]) * (Zsh[2][tid] * Zsh[3][tid]));
      __syncthreads();
    }
  }
}

// ---------------- K4: sparse PV gather -> fp16 ys (hi only) ----------------
__global__ __launch_bounds__(512) void k_pv(
    const float* __restrict__ Vp, const int* __restrict__ ccnt,
    const unsigned short* __restrict__ cidx, const float* __restrict__ cval,
    _Float16* __restrict__ ysh)
{
  const int rowc = blockIdx.x * 8 + (threadIdx.x >> 6);
  const int lane = threadIdx.x & 63;
  const int bh = rowc >> 10, n = rowc & 1023;
  const int b = bh >> 3, h = bh & 7;
  const int l0 = lane >> 5, d = lane & 31;
  const float* vA = Vp + ((b * 32 + l0 * 8 + h) << 15) + d;
  const float* vB = vA + (16 << 15);
  float y0 = 0.f, y1 = 0.f;
  for (int mcj = 0; mcj < 8; ++mcj) {
    const int cnt = min(ccnt[rowc * 8 + mcj], CAP);
    const int off = (rowc * 8 + mcj) * CAP;
    for (int i = 0; i < cnt; ++i) {
      const int m = cidx[off + i];
      const float wv = cval[off + i];
      y0 = fmaf(wv, vA[m * 32], y0);
      y1 = fmaf(wv, vB[m * 32], y1);
    }
  }
  const int idx = ((b << 10) + n) * 1024 + l0 * 256 + h * 32 + d;
  ysh[idx] = (_Float16)y0;
  ysh[idx + 512] = (_Float16)y1;
}

extern "C" void kernel_launch(void* const* d_in, const int* in_sizes, int n_in,
                              void* d_out, int out_size, void* d_ws, size_t ws_size,
                              hipStream_t stream)
{
  const float* x  = (const float*)d_in[0];
  const float* Wc = (const float*)d_in[1];
  const float* bc = (const float*)d_in[2];
  const float* Wp = (const float*)d_in[3];
  const float* bp = (const float*)d_in[4];
  float* out = (float*)d_out;
  (void)in_sizes; (void)n_in; (void)out_size;

  if (ws_size < 98828288ull) return;
  char* wsb = (char*)d_ws;
  float*          Vp   = (float*)wsb;
  _Float16*       Qs   = (_Float16*)(wsb + 16777216);
  _Float16*       Ks   = (_Float16*)(wsb + 33554432);
  _Float16*       xh   = (_Float16*)(wsb + 50855936);  // also ysh (disjoint lifetimes)
  int*            ccnt = (int*)(wsb + 67633152);
  unsigned short* cidx = (unsigned short*)(wsb + 68681728);
  float*          cval = (float*)(wsb + 77070336);
  _Float16*       Wch  = (_Float16*)(wsb + 93847552);
  _Float16*       Wcl  = (_Float16*)(wsb + 94240768);
  _Float16*       Wph  = (_Float16*)(wsb + 94633984);

  k_split_rm<<<dim3(4096), dim3(256), 0, stream>>>(x, xh, 1048576);
  k_split_tr<<<dim3(192), dim3(256), 0, stream>>>(Wc, Wch, Wcl, 256, 768);
  k_split_tr<<<dim3(1024), dim3(256), 0, stream>>>(Wp, Wph, nullptr, 1024, 1024);
  // qkv: M=16384 K=256 N=768; BN=64 -> nbn=12, grid 128*12=1536; 2-pass
  k_gemm_split<1, 2><<<dim3(1536), dim3(256), 0, stream>>>(
      xh, nullptr, Wch, Wcl, bc, 256, 2, 12, nullptr, Qs, Ks, Vp);
  // fused Z + threshold/product/emit (r9 structure, 98 us measured)
  k_att<<<dim3(512), dim3(512), 0, stream>>>(Qs, Ks, ccnt, cidx, cval);
  k_pv<<<dim3(4096), dim3(512), 0, stream>>>(Vp, ccnt, cidx, cval, xh);
  // proj: M=4096 K=1024 N=1024; BN=64 -> nbn=16, grid 32*16=512; 1-pass fp16
  k_gemm_split<0, 1><<<dim3(512), dim3(256), 0, stream>>>(
      xh, nullptr, Wph, nullptr, bp, 1024, 4, 16, out, nullptr, nullptr, nullptr);
}